// Round 5
// baseline (152.472 us; speedup 1.0000x reference)
//
#include <hip/hip_runtime.h>
#include <cmath>

// ---------------------------------------------------------------------------
// Problem constants (from reference)
// ---------------------------------------------------------------------------
constexpr int kNsh    = 9;      // (LMAX+1)^2, LMAX=2
constexpr int kF      = 64;
constexpr int kNrbf   = 20;
constexpr int kNAtoms = 1000;
constexpr int kNPairs = 10000;
constexpr float kCutoffF = 5.0f;
constexpr int kMaxNZ  = 200;
constexpr int kCp     = 12;         // channel dim padded (9 -> 12) for b128
constexpr int kXs     = kF * kCp;   // 768 floats per atom, internal layout
constexpr int kChunk  = 32;         // pairs per pd chunk in LDS
constexpr int kPdS    = 36;         // pd record stride (floats) in LDS

// ---------------------------------------------------------------------------
// Compile-time real Clebsch-Gordan table (mirrors the reference _real_cg)
// ---------------------------------------------------------------------------
struct CGSparse {
  int n;
  int c[kMaxNZ];
  int a[kMaxNZ];
  int b[kMaxNZ];
  float v[kMaxNZ];
};

constexpr double cfact(int n) {
  double r = 1.0;
  for (int i = 2; i <= n; i++) r *= (double)i;
  return r;
}
constexpr double cabs_(double x) { return x < 0 ? -x : x; }
constexpr double csqrt_(double x) {
  if (x <= 0.0) return 0.0;
  double g = x < 1.0 ? 1.0 : x;
  for (int i = 0; i < 60; i++) g = 0.5 * (g + x / g);
  return g;
}

constexpr double cg_cplx(int l1, int m1, int l2, int m2, int l3, int m3) {
  if (m3 != m1 + m2) return 0.0;
  int lo = l1 > l2 ? l1 - l2 : l2 - l1;
  if (l3 < lo || l3 > l1 + l2) return 0.0;
  double pre = csqrt_((2 * l3 + 1) * cfact(l3 + l1 - l2) * cfact(l3 - l1 + l2) *
                      cfact(l1 + l2 - l3) / cfact(l1 + l2 + l3 + 1));
  pre *= csqrt_(cfact(l3 + m3) * cfact(l3 - m3) * cfact(l1 - m1) *
                cfact(l1 + m1) * cfact(l2 - m2) * cfact(l2 + m2));
  double s = 0.0;
  for (int k = 0; k <= l1 + l2 - l3; k++) {
    int d0 = k, d1 = l1 + l2 - l3 - k, d2 = l1 - m1 - k;
    int d3 = l2 + m2 - k, d4 = l3 - l2 + m1 + k, d5 = l3 - l1 - m2 + k;
    if (d0 < 0 || d1 < 0 || d2 < 0 || d3 < 0 || d4 < 0 || d5 < 0) continue;
    double den = cfact(d0) * cfact(d1) * cfact(d2) * cfact(d3) * cfact(d4) * cfact(d5);
    s += ((k % 2) ? -1.0 : 1.0) / den;
  }
  return pre * s;
}

constexpr CGSparse build_cg() {
  CGSparse out{};
  int lidx[9] = {0, 1, 1, 1, 2, 2, 2, 2, 2};
  int midx[9] = {0, -1, 0, 1, -2, -1, 0, 1, 2};
  double Ur[9][9] = {};
  double Ui[9][9] = {};
  for (int l = 0; l <= 2; l++) {
    int base = l * l + l;
    Ur[base][base] = 1.0;
    for (int m = 1; m <= l; m++) {
      double s2 = 1.0 / csqrt_(2.0);
      double sgn = (m % 2) ? -1.0 : 1.0;
      Ur[base + m][base - m] = s2;
      Ur[base + m][base + m] = sgn * s2;
      Ui[base - m][base - m] = s2;
      Ui[base - m][base + m] = -sgn * s2;
    }
  }
  double cgr[9][9][9] = {};
  for (int i = 0; i < 9; i++)
    for (int j = 0; j < 9; j++)
      for (int k = 0; k < 9; k++) {
        double cv = cg_cplx(lidx[i], midx[i], lidx[j], midx[j], lidx[k], midx[k]);
        if (cv == 0.0) continue;
        for (int a2 = 0; a2 < 9; a2++) {
          if (Ur[a2][i] == 0.0 && Ui[a2][i] == 0.0) continue;
          for (int b2 = 0; b2 < 9; b2++) {
            if (Ur[b2][j] == 0.0 && Ui[b2][j] == 0.0) continue;
            for (int c2 = 0; c2 < 9; c2++) {
              if (Ur[c2][k] == 0.0 && Ui[c2][k] == 0.0) continue;
              double ar = Ur[a2][i], ai = Ui[a2][i];
              double br = Ur[b2][j], bi = Ui[b2][j];
              double cr = Ur[c2][k], ci = -Ui[c2][k];  // conj
              double pr = ar * br - ai * bi;
              double pi = ar * bi + ai * br;
              double rr = pr * cr - pi * ci;  // real part
              cgr[c2][a2][b2] += rr * cv;
            }
          }
        }
      }
  int n = 0;
  for (int c2 = 0; c2 < 9; c2++)
    for (int a2 = 0; a2 < 9; a2++)
      for (int b2 = 0; b2 < 9; b2++) {
        bool mask = ((lidx[a2] + lidx[b2]) % 2) == (lidx[c2] % 2);
        double v = mask ? cgr[c2][a2][b2] : 0.0;
        if (cabs_(v) > 1e-9) {
          out.c[n] = c2;
          out.a[n] = a2;
          out.b[n] = b2;
          out.v[n] = (float)v;
          n++;
        }
      }
  out.n = n;
  return out;
}

constexpr CGSparse CG = build_cg();
static_assert(CG.n > 0 && CG.n <= kMaxNZ, "CG table size out of range");

// ---------------------------------------------------------------------------
// mm_stream: acc[c] = sum_k dxLDS[c][k] * W[k][f]   (c = 0..8, k = 0..63)
// dxLDS reads are wave-uniform broadcast (conflict-free b128); W column reads
// are lane-coalesced (L2-broadcast across the 1000 blocks).
// ---------------------------------------------------------------------------
__device__ __forceinline__ void mm_stream(const float* __restrict__ sDx,
                                          const float* __restrict__ W,
                                          int f, float* __restrict__ acc) {
  #pragma unroll
  for (int c = 0; c < 9; c++) acc[c] = 0.f;
  #pragma unroll 4
  for (int kq = 0; kq < 16; kq++) {
    float w0 = W[(4 * kq + 0) * kF + f];
    float w1 = W[(4 * kq + 1) * kF + f];
    float w2 = W[(4 * kq + 2) * kF + f];
    float w3 = W[(4 * kq + 3) * kF + f];
    #pragma unroll
    for (int c = 0; c < 9; c++) {
      float4 dv = *(const float4*)(sDx + c * kF + 4 * kq);
      acc[c] += dv.x * w0 + dv.y * w1 + dv.z * w2 + dv.w * w3;
    }
  }
}

// ---------------------------------------------------------------------------
// k_so3<T>: ONE WAVE PER ATOM, barrier-free (single-wave blocks: every
// __syncthreads is a cheap intra-wave waitcnt, no cross-wave convoy).
// lane = feature f. Filters in 60 VGPRs. pd computed in-wave into LDS
// (32-pair chunks). All CG products lane-local. Matmuls: broadcast LDS
// rows x streamed W columns.
// T==0: gather emb[Z[j]] (x0 virtual), write internal [f][12] to x_out.
// T==1: gather x_in (internal), write standard [c][f] to x_out.
// ---------------------------------------------------------------------------
template <int T>
__global__ __launch_bounds__(64) void k_so3(
    const float* __restrict__ rij, const int* __restrict__ idx_i,
    const int* __restrict__ idx_j, const int* __restrict__ Z,
    const float* __restrict__ emb, const float* __restrict__ Wft,
    const float* __restrict__ bft, const float* __restrict__ W1,
    const float* __restrict__ W2, const float* __restrict__ W3,
    const float* __restrict__ Wg, const float* __restrict__ bg,
    const float* __restrict__ x_in, float* __restrict__ x_out) {
  const int atom = blockIdx.x;
  const int f = threadIdx.x;          // lane 0..63

  __shared__ __align__(16) float pdLDS[kChunk * kPdS];  // 4.6 KB
  __shared__ __align__(16) float dxLDS[kNsh * kF];      // 2.3 KB
  __shared__ __align__(16) float rowLDS[kF];            // 256 B

  // ---- filters into registers (dead after message phase) ----
  float w0r[kNrbf], w1r[kNrbf], w2r[kNrbf];
  #pragma unroll
  for (int k = 0; k < kNrbf; k++) {
    w0r[k] = Wft[k * 192 + f];
    w1r[k] = Wft[k * 192 + 64 + f];
    w2r[k] = Wft[k * 192 + 128 + f];
  }
  const float bf0 = bft[f], bf1 = bft[64 + f], bf2 = bft[128 + f];

  // ---- seg: lanes (f&1) search atom / atom+1; broadcast via readlane ----
  int lo = 0;
  {
    const int a = atom + (f & 1);
    int hi = kNPairs;
    while (lo < hi) {
      int mid = (lo + hi) >> 1;
      if (idx_i[mid] < a) lo = mid + 1; else hi = mid;
    }
  }
  const int s0 = __builtin_amdgcn_readlane(lo, 0);
  const int s1 = __builtin_amdgcn_readlane(lo, 1);

  // ---- message: chunks of <=32 pairs; pd into LDS, then accumulate y ----
  float y[9];
  #pragma unroll
  for (int c = 0; c < 9; c++) y[c] = 0.f;

  for (int cb = s0; cb < s1; cb += kChunk) {
    const int cn = (s1 - cb < kChunk) ? (s1 - cb) : kChunk;
    // pd records: slot 0..8 = Y, 9 = cut, 12..31 = radial*cut (10,11 unused)
    for (int item = f; item < cn * 32; item += 64) {
      const int pp = item >> 5, slot = item & 31;
      const int p = cb + pp;
      float rx = rij[3 * p + 0], ry = rij[3 * p + 1], rz = rij[3 * p + 2];
      float d = sqrtf(rx * rx + ry * ry + rz * rz);
      float inv = 1.0f / d;
      float ux = rx * inv, uy = ry * inv, uz = rz * inv;
      const float c0 = 0.28209479177387814f;  // 0.5/sqrt(pi)
      const float c1 = 0.4886025119029199f;   // sqrt(3/(4pi))
      const float c2 = 1.0925484305920792f;   // 0.5*sqrt(15/pi)
      const float c3 = 0.31539156525252005f;  // 0.25*sqrt(5/pi)
      const float c4 = 0.5462742152960396f;   // 0.25*sqrt(15/pi)
      float cut = (d < kCutoffF) ? 0.5f * (cosf(d * (float)(M_PI / 5.0)) + 1.0f) : 0.0f;
      float val;
      if (slot < 9) {
        val =
            (slot == 0) ? c0 :
            (slot == 1) ? c1 * uy :
            (slot == 2) ? c1 * uz :
            (slot == 3) ? c1 * ux :
            (slot == 4) ? c2 * ux * uy :
            (slot == 5) ? c2 * uy * uz :
            (slot == 6) ? c3 * (3.0f * uz * uz - 1.0f) :
            (slot == 7) ? c2 * ux * uz :
                          c4 * (ux * ux - uy * uy);
      } else if (slot == 9) {
        val = cut;
      } else if (slot >= 12) {
        const float width = kCutoffF / (kNrbf - 1);
        const float coef = -0.5f / (width * width);
        float off = (kCutoffF * (slot - 12)) / (kNrbf - 1);
        float tt = d - off;
        val = expf(coef * tt * tt) * cut;   // radial*cut (bias uses cut)
      } else {
        continue;   // slots 10, 11 unused
      }
      pdLDS[pp * kPdS + slot] = val;
    }
    __syncthreads();  // single-wave: compiles to waitcnt, no convoy

    for (int pp = 0; pp < cn; pp++) {
      const int p = cb + pp;
      const int j = idx_j[p];                  // wave-uniform
      const float* pd = pdLDS + pp * kPdS;
      const float cut = pd[9];
      float Wl0 = bf0 * cut, Wl1 = bf1 * cut, Wl2 = bf2 * cut;
      #pragma unroll
      for (int kq = 0; kq < 5; kq++) {
        float4 r4 = *(const float4*)(pd + 12 + 4 * kq);
        Wl0 += r4.x * w0r[4 * kq] + r4.y * w0r[4 * kq + 1] +
               r4.z * w0r[4 * kq + 2] + r4.w * w0r[4 * kq + 3];
        Wl1 += r4.x * w1r[4 * kq] + r4.y * w1r[4 * kq + 1] +
               r4.z * w1r[4 * kq + 2] + r4.w * w1r[4 * kq + 3];
        Wl2 += r4.x * w2r[4 * kq] + r4.y * w2r[4 * kq + 1] +
               r4.z * w2r[4 * kq + 2] + r4.w * w2r[4 * kq + 3];
      }
      float YW[9];
      YW[0] = pd[0] * Wl0;
      YW[1] = pd[1] * Wl1;
      YW[2] = pd[2] * Wl1;
      YW[3] = pd[3] * Wl1;
      #pragma unroll
      for (int b = 4; b < 9; b++) YW[b] = pd[b] * Wl2;
      if (T == 0) {
        // x[j] = emb[Z[j]] in channel 0 only: CG folds to a==0 entries
        float e = emb[Z[j] * kF + f];
        #pragma unroll
        for (int q = 0; q < CG.n; q++) {
          if (CG.a[q] == 0) y[CG.c[q]] += CG.v[q] * YW[CG.b[q]] * e;
        }
      } else {
        const float* xj = x_in + j * kXs + f * kCp;
        float xv[12];
        *(float4*)&xv[0] = *(const float4*)(xj + 0);
        *(float4*)&xv[4] = *(const float4*)(xj + 4);
        *(float4*)&xv[8] = *(const float4*)(xj + 8);
        #pragma unroll
        for (int q = 0; q < CG.n; q++) {
          y[CG.c[q]] += CG.v[q] * YW[CG.b[q]] * xv[CG.a[q]];
        }
      }
    }
    __syncthreads();  // WAR: next chunk overwrites pdLDS
  }

  // ---- update (all lane-local except broadcast LDS rows) ----
  // mm1: ddx = dx @ W1
  #pragma unroll
  for (int c = 0; c < 9; c++) dxLDS[c * kF + f] = y[c];
  __syncthreads();
  float ddx[9];
  mm_stream(dxLDS, W1, f, ddx);

  // t2 = dx + CG(dx, ddx)   (purely lane-local)
  float t2[9];
  #pragma unroll
  for (int c = 0; c < 9; c++) t2[c] = y[c];
  #pragma unroll
  for (int q = 0; q < CG.n; q++) {
    t2[CG.c[q]] += CG.v[q] * y[CG.a[q]] * ddx[CG.b[q]];
  }

  // mm2: dx2 = t2 @ W2
  __syncthreads();  // WAR on dxLDS
  #pragma unroll
  for (int c = 0; c < 9; c++) dxLDS[c * kF + f] = t2[c];
  __syncthreads();
  float dx2[9];
  mm_stream(dxLDS, W2, f, dx2);

  // gate = sigmoid(dx2[0] @ Wg + bg)
  rowLDS[f] = dx2[0];
  __syncthreads();
  float g0 = bg[f], g1 = bg[64 + f], g2 = bg[128 + f];
  #pragma unroll 4
  for (int kq = 0; kq < 16; kq++) {
    float4 a4 = *(const float4*)(rowLDS + 4 * kq);
    float av[4] = {a4.x, a4.y, a4.z, a4.w};
    #pragma unroll
    for (int qq = 0; qq < 4; qq++) {
      const int k = 4 * kq + qq;
      g0 += av[qq] * Wg[k * 192 + f];
      g1 += av[qq] * Wg[k * 192 + 64 + f];
      g2 += av[qq] * Wg[k * 192 + 128 + f];
    }
  }
  g0 = 1.f / (1.f + expf(-g0));
  g1 = 1.f / (1.f + expf(-g1));
  g2 = 1.f / (1.f + expf(-g2));

  float dx3[9];
  dx3[0] = dx2[0] * g0;
  dx3[1] = dx2[1] * g1;
  dx3[2] = dx2[2] * g1;
  dx3[3] = dx2[3] * g1;
  #pragma unroll
  for (int c = 4; c < 9; c++) dx3[c] = dx2[c] * g2;

  // mm3: o = dx3 @ W3
  __syncthreads();  // WAR on dxLDS
  #pragma unroll
  for (int c = 0; c < 9; c++) dxLDS[c * kF + f] = dx3[c];
  __syncthreads();
  float o[9];
  mm_stream(dxLDS, W3, f, o);

  // ---- residual + store ----
  if (T == 0) {
    // residual = emb[Z[atom]] at channel 0; internal layout [f][12]
    float r0 = emb[Z[atom] * kF + f];
    float buf[12];
    #pragma unroll
    for (int c = 0; c < 9; c++) buf[c] = o[c];
    buf[0] += r0;
    buf[9] = 0.f; buf[10] = 0.f; buf[11] = 0.f;
    float* dst = x_out + atom * kXs + f * kCp;
    *(float4*)(dst + 0) = *(float4*)&buf[0];
    *(float4*)(dst + 4) = *(float4*)&buf[4];
    *(float4*)(dst + 8) = *(float4*)&buf[8];
  } else {
    // residual = x_in (internal); output standard [c][f]
    const float* xi = x_in + atom * kXs + f * kCp;
    float xv[12];
    *(float4*)&xv[0] = *(const float4*)(xi + 0);
    *(float4*)&xv[4] = *(const float4*)(xi + 4);
    *(float4*)&xv[8] = *(const float4*)(xi + 8);
    #pragma unroll
    for (int c = 0; c < 9; c++) {
      x_out[atom * (kNsh * kF) + c * kF + f] = o[c] + xv[c];
    }
  }
}

// ---------------------------------------------------------------------------
// Launch: 2 dispatches; only workspace is x1 (internal-layout intermediate)
// ---------------------------------------------------------------------------
extern "C" void kernel_launch(void* const* d_in, const int* in_sizes, int n_in,
                              void* d_out, int out_size, void* d_ws, size_t ws_size,
                              hipStream_t stream) {
  const int* Z        = (const int*)d_in[0];
  const float* rij    = (const float*)d_in[1];
  const int* idx_i    = (const int*)d_in[2];
  const int* idx_j    = (const int*)d_in[3];
  const float* emb    = (const float*)d_in[4];
  const float* Wf     = (const float*)d_in[5];
  const float* bf     = (const float*)d_in[6];
  const float* W1     = (const float*)d_in[7];
  const float* W2     = (const float*)d_in[8];
  const float* W3     = (const float*)d_in[9];
  const float* Wg     = (const float*)d_in[10];
  const float* bg     = (const float*)d_in[11];
  float* out = (float*)d_out;

  float* x1 = (float*)d_ws;   // 768,000 floats (internal layout)

  // t = 0: emb-gather -> x1 (internal layout)
  k_so3<0><<<kNAtoms, 64, 0, stream>>>(
      rij, idx_i, idx_j, Z, emb, Wf, bf,
      W1, W2, W3, Wg, bg, (const float*)nullptr, x1);

  // t = 1: x1-gather -> d_out (standard layout)
  k_so3<1><<<kNAtoms, 64, 0, stream>>>(
      rij, idx_i, idx_j, Z, emb, Wf + kNrbf * 192, bf + 192,
      W1 + kF * kF, W2 + kF * kF, W3 + kF * kF,
      Wg + kF * 192, bg + 192, x1, out);
}